// Round 5
// baseline (266.624 us; speedup 1.0000x reference)
//
#include <hip/hip_runtime.h>
#include <math.h>

#define NROWS   65536
#define DIMS    64
#define KCODES  1024
#define XL      132   // LDS row stride (pad)

static constexpr size_t QST_OFF  = 0;         // quantized_st [65536*64]
static constexpr size_t LOSS_OFF = 4194304;   // loss scalar
static constexpr size_t PERP_OFF = 4194305;   // perplexity scalar
static constexpr size_t ENC_OFF  = 4194306;   // encodings [65536*1024]
static constexpr size_t IDX_OFF  = 71303170;  // encoding_indices [65536]
static constexpr size_t DIST_OFF = 71368706;  // distances [65536*1024]

// ||e_k||^2 per np.sum(np.square(emb),0): sequential d, mul then add (no fma).
// Also builds emb_T[k][d] for the coalesced qst gather.
__global__ void prep_kernel(const float* __restrict__ emb, float* __restrict__ enorm,
                            float* __restrict__ embT) {
    #pragma clang fp contract(off)
    int k = blockIdx.x * blockDim.x + threadIdx.x;   // 0..1023
    float s = 0.f;
    for (int d = 0; d < DIMS; ++d) {
        float e = emb[(size_t)d * KCODES + k];
        embT[(size_t)k * DIMS + d] = e;
        float sq = e * e;
        s = s + sq;
    }
    enorm[k] = s;
}

__global__ __launch_bounds__(512, 4) void vq_fused(
    const float* __restrict__ x, const float* __restrict__ emb,
    const float* __restrict__ enorm, const float* __restrict__ embT,
    float* __restrict__ out, float* __restrict__ counts, float* __restrict__ sqsum)
{
    #pragma clang fp contract(off)
    __shared__ __align__(16) float xs[DIMS * XL];    // [d][row], 33.8 KB
    __shared__ __align__(16) float es[2][32 * XL];   // dbuf [d2][k_local], 33.8 KB
    __shared__ float xn[128];
    __shared__ int   winner[128];
    __shared__ float bsum[8];

    const int tid = threadIdx.x;
    const int tc  = tid & 15;      // k-lane
    const int tr  = tid >> 4;      // row-group 0..31 (rows tr*4..+3)
    const size_t n0 = (size_t)blockIdx.x * 128;
    const float* xg = x + n0 * DIMS;

    // ---- stage x transposed: thread's row fixed (tid&127), 4 d-quads ----
    #pragma unroll
    for (int i = 0; i < 4; ++i) {
        int c = tid + 512 * i;
        int row = c & 127, dq = c >> 7;          // dq 0..15
        float4 v = *(const float4*)(xg + (size_t)row * DIMS + dq * 4);
        xs[(dq * 4 + 0) * XL + row] = v.x;
        xs[(dq * 4 + 1) * XL + row] = v.y;
        xs[(dq * 4 + 2) * XL + row] = v.z;
        xs[(dq * 4 + 3) * XL + row] = v.w;
    }
    // prologue e-stage for step 0 (kt=0,h=0)
    {
        int c0 = tid, c1 = tid + 512;            // kq=c&31, d2=c>>5
        float4 a = *(const float4*)(emb + (size_t)(c0 >> 5) * KCODES + (c0 & 31) * 4);
        float4 b = *(const float4*)(emb + (size_t)(c1 >> 5) * KCODES + (c1 & 31) * 4);
        __syncthreads();   // x-stage writes done before xn reads; also fences es reuse
        *(float4*)&es[0][(c0 >> 5) * XL + (c0 & 31) * 4] = a;
        *(float4*)&es[0][(c1 >> 5) * XL + (c1 & 31) * 4] = b;
    }
    // ||x||^2: numpy pairwise (8 accs, mul-then-add, 3-level combine)
    if (tid < 128) {
        float rr[8];
        #pragma unroll
        for (int j = 0; j < 8; ++j) { float v = xs[j * XL + tid]; rr[j] = v * v; }
        for (int i = 8; i < 64; i += 8)
            #pragma unroll
            for (int j = 0; j < 8; ++j) { float v = xs[(i + j) * XL + tid]; float sq = v * v; rr[j] = rr[j] + sq; }
        xn[tid] = ((rr[0] + rr[1]) + (rr[2] + rr[3])) + ((rr[4] + rr[5]) + (rr[6] + rr[7]));
    }
    __syncthreads();

    float acc[4][8];
    float bv[4]; int bi[4];
    #pragma unroll
    for (int j = 0; j < 4; ++j) { bv[j] = 3.4e38f; bi[j] = 0; }
    float4 en0, en1;
    const float4 z4 = make_float4(0.f, 0.f, 0.f, 0.f);

    for (int s = 0; s < 16; ++s) {
        const int kt = s >> 1, h = s & 1, buf = s & 1;
        if (h == 0) {
            #pragma unroll
            for (int j = 0; j < 4; ++j)
                #pragma unroll
                for (int m = 0; m < 8; ++m) acc[j][m] = 0.f;
            en0 = *(const float4*)(enorm + kt * 128 + tc * 4);
            en1 = *(const float4*)(enorm + kt * 128 + 64 + tc * 4);
        }
        // issue next-step e loads (stay in flight across the FMA section)
        float4 nt0, nt1;
        if (s < 15) {
            int sn = s + 1, ktn = sn >> 1, hn = sn & 1;
            int c0 = tid, c1 = tid + 512;
            nt0 = *(const float4*)(emb + (size_t)(hn * 32 + (c0 >> 5)) * KCODES + ktn * 128 + (c0 & 31) * 4);
            nt1 = *(const float4*)(emb + (size_t)(hn * 32 + (c1 >> 5)) * KCODES + ktn * 128 + (c1 & 31) * 4);
        }
        // FMA: sequential-d single-fma-chain per (row,k) — matches np sgemm
        const float* ep = es[buf];
        const int dbase = h * 32;
        #pragma unroll 4
        for (int d2 = 0; d2 < 32; ++d2) {
            float4 xr = *(const float4*)&xs[(dbase + d2) * XL + tr * 4];
            float4 ea = *(const float4*)&ep[d2 * XL + tc * 4];
            float4 eb = *(const float4*)&ep[d2 * XL + 64 + tc * 4];
            float xv[4] = {xr.x, xr.y, xr.z, xr.w};
            #pragma unroll
            for (int j = 0; j < 4; ++j) {
                acc[j][0] = fmaf(xv[j], ea.x, acc[j][0]);
                acc[j][1] = fmaf(xv[j], ea.y, acc[j][1]);
                acc[j][2] = fmaf(xv[j], ea.z, acc[j][2]);
                acc[j][3] = fmaf(xv[j], ea.w, acc[j][3]);
                acc[j][4] = fmaf(xv[j], eb.x, acc[j][4]);
                acc[j][5] = fmaf(xv[j], eb.y, acc[j][5]);
                acc[j][6] = fmaf(xv[j], eb.z, acc[j][6]);
                acc[j][7] = fmaf(xv[j], eb.w, acc[j][7]);
            }
        }
        if (h == 1) {   // epilogue for this k-tile: dist+enc stores spread in time
            #pragma unroll
            for (int j = 0; j < 4; ++j) {
                const int row = tr * 4 + j;
                const float xnr = xn[row];
                float4 da, db;
                { float m = 2.0f * acc[j][0]; float t = xnr - m; da.x = t + en0.x; }
                { float m = 2.0f * acc[j][1]; float t = xnr - m; da.y = t + en0.y; }
                { float m = 2.0f * acc[j][2]; float t = xnr - m; da.z = t + en0.z; }
                { float m = 2.0f * acc[j][3]; float t = xnr - m; da.w = t + en0.w; }
                { float m = 2.0f * acc[j][4]; float t = xnr - m; db.x = t + en1.x; }
                { float m = 2.0f * acc[j][5]; float t = xnr - m; db.y = t + en1.y; }
                { float m = 2.0f * acc[j][6]; float t = xnr - m; db.z = t + en1.z; }
                { float m = 2.0f * acc[j][7]; float t = xnr - m; db.w = t + en1.w; }
                const size_t rowg = n0 + row;
                float* dr = out + DIST_OFF + rowg * (size_t)KCODES + kt * 128 + tc * 4;
                *(float4*)dr = da; *(float4*)(dr + 64) = db;
                float* er = out + ENC_OFF + rowg * (size_t)KCODES + kt * 128 + tc * 4;
                *(float4*)er = z4; *(float4*)(er + 64) = z4;

                // local argmin, ascending k (strict less = first-index tie-break)
                float lv = da.x; int li = kt * 128 + tc * 4;
                if (da.y < lv) { lv = da.y; li = kt * 128 + tc * 4 + 1; }
                if (da.z < lv) { lv = da.z; li = kt * 128 + tc * 4 + 2; }
                if (da.w < lv) { lv = da.w; li = kt * 128 + tc * 4 + 3; }
                if (db.x < lv) { lv = db.x; li = kt * 128 + 64 + tc * 4; }
                if (db.y < lv) { lv = db.y; li = kt * 128 + 64 + tc * 4 + 1; }
                if (db.z < lv) { lv = db.z; li = kt * 128 + 64 + tc * 4 + 2; }
                if (db.w < lv) { lv = db.w; li = kt * 128 + 64 + tc * 4 + 3; }
                if (lv < bv[j]) { bv[j] = lv; bi[j] = li; }   // earlier kt wins ties
            }
        }
        if (s < 15) {   // double-buffer write for next step
            int bufn = (s + 1) & 1;
            int c0 = tid, c1 = tid + 512;
            *(float4*)&es[bufn][(c0 >> 5) * XL + (c0 & 31) * 4] = nt0;
            *(float4*)&es[bufn][(c1 >> 5) * XL + (c1 & 31) * 4] = nt1;
        }
        // raw barrier: wait LDS only — global stores stay in flight
        asm volatile("s_waitcnt lgkmcnt(0)" ::: "memory");
        __builtin_amdgcn_s_barrier();
    }

    __syncthreads();   // full drain: enc zeros complete before one-hot 1.0

    // per-row final argmin across the 16 k-lanes (u64 key: exact float order, min-k tie)
    #pragma unroll
    for (int j = 0; j < 4; ++j) {
        const int row = tr * 4 + j;
        int ib = __float_as_int(bv[j]);
        unsigned mk = (unsigned)ib ^ ((unsigned)(ib >> 31) | 0x80000000u);
        unsigned long long key = ((unsigned long long)mk << 32) | (unsigned)bi[j];
        #pragma unroll
        for (int m = 1; m < 16; m <<= 1) {
            unsigned long long ok = __shfl_xor(key, m);
            if (ok < key) key = ok;
        }
        if (tc == 0) {
            int k = (int)(key & 1023u);
            winner[row] = k;
            out[IDX_OFF + n0 + row] = (float)k;
            atomicAdd(&counts[k], 1.0f);
            out[ENC_OFF + (n0 + row) * (size_t)KCODES + k] = 1.0f;
        }
    }
    __syncthreads();

    // qst gather (coalesced via emb_T) + squared-error accumulation
    {
        const int row = tid >> 2;
        const int q4  = tid & 3;                  // d-range q4*16..+16
        const int k   = winner[row];
        const float* et = embT + (size_t)k * DIMS + q4 * 16;
        float* qo = out + QST_OFF + (n0 + row) * (size_t)DIMS + q4 * 16;
        float ls = 0.f;
        #pragma unroll
        for (int i = 0; i < 4; ++i) {
            float4 q = *(const float4*)(et + 4 * i);
            *(float4*)(qo + 4 * i) = q;
            float f0 = q.x - xs[(q4 * 16 + 4 * i + 0) * XL + row];
            float f1 = q.y - xs[(q4 * 16 + 4 * i + 1) * XL + row];
            float f2 = q.z - xs[(q4 * 16 + 4 * i + 2) * XL + row];
            float f3 = q.w - xs[(q4 * 16 + 4 * i + 3) * XL + row];
            ls += f0 * f0 + f1 * f1 + f2 * f2 + f3 * f3;
        }
        #pragma unroll
        for (int m = 1; m < 64; m <<= 1) ls += __shfl_xor(ls, m);
        if ((tid & 63) == 0) bsum[tid >> 6] = ls;
    }
    __syncthreads();
    if (tid == 0) {
        float s = 0.f;
        #pragma unroll
        for (int i = 0; i < 8; ++i) s += bsum[i];
        atomicAdd(sqsum, s);
    }
}

__global__ void vq_final(const float* __restrict__ counts, const float* __restrict__ sqsum,
                         float* __restrict__ out) {
    __shared__ double part[16];
    int tid = threadIdx.x;  // 1024 threads
    double p = (double)counts[tid] * (1.0 / 65536.0);
    double t = p * log(p + 1e-10);
    #pragma unroll
    for (int m = 1; m < 64; m <<= 1) t += __shfl_xor(t, m);
    if ((tid & 63) == 0) part[tid >> 6] = t;
    __syncthreads();
    if (tid == 0) {
        double s = 0.0;
        #pragma unroll
        for (int i = 0; i < 16; ++i) s += part[i];
        out[LOSS_OFF] = (float)(1.25 * (double)sqsum[0] * (1.0 / 4194304.0));
        out[PERP_OFF] = (float)exp(-s);
    }
}

extern "C" void kernel_launch(void* const* d_in, const int* in_sizes, int n_in,
                              void* d_out, int out_size, void* d_ws, size_t ws_size,
                              hipStream_t stream) {
    const float* x   = (const float*)d_in[0];   // (64,32,32,64) fp32
    const float* emb = (const float*)d_in[1];   // (64,1024) fp32
    float* out = (float*)d_out;
    // ws (floats): enorm[0,1024) | counts[1024,2048) | sqsum[2048] | embT at 4096 (64K floats)
    float* enorm  = (float*)d_ws;
    float* counts = enorm + KCODES;
    float* sqsum  = counts + KCODES;
    float* embT   = (float*)d_ws + 4096;

    hipMemsetAsync(counts, 0, (KCODES + 1) * sizeof(float), stream);   // counts + sqsum
    prep_kernel<<<KCODES / 256, 256, 0, stream>>>(emb, enorm, embT);
    vq_fused<<<NROWS / 128, 512, 0, stream>>>(x, emb, enorm, embT, out, counts, sqsum);
    vq_final<<<1, KCODES, 0, stream>>>(counts, sqsum, out);
}